// Round 8
// baseline (514.950 us; speedup 1.0000x reference)
//
#include <hip/hip_runtime.h>
#include <hip/hip_bf16.h>

#define NUU 50000
#define NMM 20000
#define NT (NUU + NMM)
#define FEAT 32
#define NE 262144
#define NEL 100000
#define HD 512
#define EDIM 7
#define NC 7

typedef __hip_bfloat16 bf16;
typedef __attribute__((ext_vector_type(8))) short short8;
typedef __attribute__((ext_vector_type(4))) float f32x4;

__device__ __forceinline__ float b2f(unsigned short u)
{
  return __uint_as_float((unsigned)u << 16);
}
__device__ __forceinline__ unsigned short f2bbits(float x)
{
  __hip_bfloat16 h = __float2bfloat16(x);
  return *reinterpret_cast<unsigned short*>(&h);
}
__device__ __forceinline__ float2 ld2(const float* p) { return *(const float2*)p; }
__device__ __forceinline__ void st2b(bf16* p, float x, float y)
{
  ushort2 u = make_ushort2(f2bbits(x), f2bbits(y));
  *(ushort2*)p = u;
}
__device__ __forceinline__ void gload16(const void* g, void* l)
{
  __builtin_amdgcn_global_load_lds(
      (const __attribute__((address_space(1))) void*)g,
      (__attribute__((address_space(3))) void*)l, 16, 0, 0);
}

// ---- merged prep: blocks [0,1024) encoder; [1024,2048) fp32->bf16 cvt of user_emb ----
__global__ __launch_bounds__(256) void prep_k(
    const float* __restrict__ mx, const float* __restrict__ W,
    const float* __restrict__ b, const float* __restrict__ emb,
    bf16* __restrict__ xm, const float* __restrict__ uin, bf16* __restrict__ ubf)
{
  const int tid = threadIdx.x;
  if (blockIdx.x < 1024) {
    const int c0 = 2 * tid;
    float2 wreg[FEAT];
#pragma unroll
    for (int k = 0; k < FEAT; ++k) wreg[k] = ld2(&W[(size_t)k * HD + c0]);
    const float2 bv = ld2(&b[c0]);
    __shared__ float xr[FEAT];
    for (int m = blockIdx.x; m < NMM; m += 1024) {
      if (tid < FEAT) xr[tid] = mx[(size_t)m * FEAT + tid];
      __syncthreads();
      float2 e2 = ld2(&emb[(size_t)m * HD + c0]);
      float s0 = bv.x + e2.x, s1 = bv.y + e2.y;
#pragma unroll
      for (int k = 0; k < FEAT; ++k) {
        s0 += xr[k] * wreg[k].x;
        s1 += xr[k] * wreg[k].y;
      }
      st2b(&xm[(size_t)m * HD + c0], s0, s1);
      __syncthreads();
    }
  } else {
    const int n4 = NUU * HD / 4;
    for (int i = (blockIdx.x - 1024) * 256 + tid; i < n4; i += 1024 * 256) {
      float4 v = *(const float4*)&uin[4 * (size_t)i];
      ushort4 u = make_ushort4(f2bbits(v.x), f2bbits(v.y), f2bbits(v.z), f2bbits(v.w));
      *(ushort4*)&ubf[4 * (size_t)i] = u;
    }
  }
}

// ---- merged Wcat transpose (z picks param set) ----
__global__ __launch_bounds__(256) void wtrans_k(
    const float* __restrict__ lwA, const float* __restrict__ rwA, bf16* __restrict__ WcA,
    const float* __restrict__ lwB, const float* __restrict__ rwB, bf16* __restrict__ WcB)
{
  const float* lw = blockIdx.z ? lwB : lwA;
  const float* rw = blockIdx.z ? rwB : rwA;
  bf16* Wcat = blockIdx.z ? WcB : WcA;
  __shared__ float s[32][33];
  const int tx = threadIdx.x & 31;
  const int ty = threadIdx.x >> 5;
  const int nt = blockIdx.x * 32;
  const int kt = blockIdx.y * 32;
#pragma unroll
  for (int q = 0; q < 4; ++q) {
    int k = kt + q * 8 + ty;
    int n = nt + tx;
    float v = (k < HD) ? lw[(size_t)k * HD + n] : rw[(size_t)(k - HD) * HD + n];
    s[q * 8 + ty][tx] = v;
  }
  __syncthreads();
#pragma unroll
  for (int q = 0; q < 4; ++q) {
    int n = nt + q * 8 + ty;
    int k = kt + tx;
    Wcat[(size_t)n * (2 * HD) + k] = __float2bfloat16(s[tx][q * 8 + ty]);
  }
}

// ---- single edge pass: degree count + per-dst edge-attr sums (coalesced ea reads) ----
__global__ void edge_pass_k(const int* __restrict__ dmu, const int* __restrict__ dum,
                            const float* __restrict__ eaMU, const float* __restrict__ eaUM,
                            int* __restrict__ cnt, float* __restrict__ eaSum)
{
  for (int i = blockIdx.x * blockDim.x + threadIdx.x; i < NE; i += gridDim.x * blockDim.x) {
    int d0 = dmu[i];
    int d1 = NUU + dum[i];
    atomicAdd(&cnt[d0], 1);
    atomicAdd(&cnt[d1], 1);
#pragma unroll
    for (int c = 0; c < NC; ++c) {
      atomicAdd(&eaSum[(size_t)d0 * 8 + c], eaMU[(size_t)i * EDIM + c]);
      atomicAdd(&eaSum[(size_t)d1 * 8 + c], eaUM[(size_t)i * EDIM + c]);
    }
  }
}

__global__ __launch_bounds__(512) void scan_a512(const int* __restrict__ in,
                                                 int* __restrict__ out,
                                                 int* __restrict__ bsum, int n)
{
  __shared__ int s[512];
  const int tid = threadIdx.x;
  const int i = blockIdx.x * 512 + tid;
  int v = (i < n) ? in[i] : 0;
  s[tid] = v;
  __syncthreads();
  for (int d = 1; d < 512; d <<= 1) {
    int t = (tid >= d) ? s[tid - d] : 0;
    __syncthreads();
    s[tid] += t;
    __syncthreads();
  }
  if (i < n) out[i] = s[tid] - v;           // exclusive
  if (tid == 511) bsum[blockIdx.x] = s[511];
}

__global__ void scan_b256(int* __restrict__ bsum, int nb)
{
  __shared__ int s[256];
  const int tid = threadIdx.x;
  int v = (tid < nb) ? bsum[tid] : 0;
  s[tid] = v;
  __syncthreads();
  for (int d = 1; d < 256; d <<= 1) {
    int t = (tid >= d) ? s[tid - d] : 0;
    __syncthreads();
    s[tid] += t;
    __syncthreads();
  }
  if (tid < nb) bsum[tid] = s[tid] - v;     // exclusive
}

__global__ __launch_bounds__(512) void scan_c512(int* __restrict__ out,
                                                 const int* __restrict__ bsum, int n)
{
  const int i = blockIdx.x * 512 + threadIdx.x;
  if (i < n) out[i] += bsum[blockIdx.x];
}

// fill CSR with source node id only
__global__ void fill2_k(const int* __restrict__ smu, const int* __restrict__ dmu,
                        const int* __restrict__ sum_, const int* __restrict__ dum,
                        const int* __restrict__ off, int* __restrict__ fill,
                        int* __restrict__ csrS)
{
  for (int i = blockIdx.x * blockDim.x + threadIdx.x; i < NE; i += gridDim.x * blockDim.x) {
    int d0 = dmu[i];
    int p0 = off[d0] + atomicAdd(&fill[d0], 1);
    csrS[p0] = smu[i];
    int d1 = NUU + dum[i];
    int p1 = off[d1] + atomicAdd(&fill[d1], 1);
    csrS[p1] = sum_[i];
  }
}

// ---- folded classifier weights, both param sets in one launch (blockIdx.y) ----
__global__ __launch_bounds__(64) void projw_k(
    const float* __restrict__ lwA, const float* __restrict__ rwA,
    const float* __restrict__ lbA, const float* __restrict__ clsW,
    float* __restrict__ WlA, float* __restrict__ WrA, float* __restrict__ ccA,
    const float* __restrict__ lwB, const float* __restrict__ rwB,
    const float* __restrict__ lbB,
    float* __restrict__ WlB, float* __restrict__ WrB, float* __restrict__ ccB)
{
  const int side = blockIdx.y;
  const float* lw = side ? lwB : lwA;
  const float* rw = side ? rwB : rwA;
  const float* lb = side ? lbB : lbA;
  const float* cw = clsW + (side ? (size_t)HD * NC : 0);
  float* Wl = side ? WlB : WlA;
  float* Wr = side ? WrB : WrA;
  float* cc = side ? ccB : ccA;
  const int k = blockIdx.x;
  const int l = threadIdx.x;
  if (k < HD) {
    float aL[NC] = {0, 0, 0, 0, 0, 0, 0};
    float aR[NC] = {0, 0, 0, 0, 0, 0, 0};
    for (int j = l; j < HD; j += 64) {
      float a = lw[(size_t)k * HD + j];
      float b = rw[(size_t)k * HD + j];
#pragma unroll
      for (int c = 0; c < NC; ++c) {
        float w = cw[(size_t)j * NC + c];
        aL[c] += a * w;
        aR[c] += b * w;
      }
    }
#pragma unroll
    for (int c = 0; c < NC; ++c)
      for (int s = 32; s; s >>= 1) {
        aL[c] += __shfl_xor(aL[c], s);
        aR[c] += __shfl_xor(aR[c], s);
      }
    if (l == 0) {
#pragma unroll
      for (int c = 0; c < NC; ++c) {
        Wl[k * NC + c] = aL[c];
        Wr[k * NC + c] = aR[c];
      }
    }
  } else {
    float a0[NC] = {0, 0, 0, 0, 0, 0, 0};
    for (int j = l; j < HD; j += 64) {
      float a = lb[j];
#pragma unroll
      for (int c = 0; c < NC; ++c) a0[c] += a * cw[(size_t)j * NC + c];
    }
#pragma unroll
    for (int c = 0; c < NC; ++c)
      for (int s = 32; s; s >>= 1) a0[c] += __shfl_xor(a0[c], s);
    if (l == 0) {
#pragma unroll
      for (int c = 0; c < NC; ++c) cc[c] = a0[c];
    }
  }
}

// ---- merged: blocks 0..3 = proj2 fold; blocks 4..67 = W2t pack ----
__global__ __launch_bounds__(256) void p2w2t_k(
    const float* __restrict__ ewA, const float* __restrict__ ebA,
    const float* __restrict__ WlA, float* __restrict__ ewPA, float* __restrict__ ebPA,
    const float* __restrict__ ewB, const float* __restrict__ ebB,
    const float* __restrict__ WlB, float* __restrict__ ewPB, float* __restrict__ ebPB,
    const float* __restrict__ WAu, const float* __restrict__ WBu, bf16* __restrict__ W2u,
    const float* __restrict__ WAm, const float* __restrict__ WBm, bf16* __restrict__ W2m)
{
  const int b = blockIdx.x;
  if (b < 4) {
    const int side = b >> 1;
    const float* ew = side ? ewB : ewA;
    const float* ebv = side ? ebB : ebA;
    const float* Wl = side ? WlB : WlA;
    float* ewP = side ? ewPB : ewPA;
    float* ebP = side ? ebPB : ebPA;
    const int j = (b & 1) * 4 + (threadIdx.x >> 6);
    const int l = threadIdx.x & 63;
    const float* __restrict__ src = (j < 7) ? &ew[(size_t)j * HD] : ebv;
    float acc[NC] = {0, 0, 0, 0, 0, 0, 0};
    for (int k = l; k < HD; k += 64) {
      float v = src[k];
#pragma unroll
      for (int c = 0; c < NC; ++c) acc[c] += v * Wl[(size_t)k * NC + c];
    }
#pragma unroll
    for (int c = 0; c < NC; ++c)
      for (int s = 32; s; s >>= 1) acc[c] += __shfl_xor(acc[c], s);
    if (l == 0) {
      if (j < 7) {
#pragma unroll
        for (int c = 0; c < NC; ++c) ewP[j * 8 + c] = acc[c];
        ewP[j * 8 + 7] = 0.f;
      } else {
#pragma unroll
        for (int c = 0; c < NC; ++c) ebP[c] = acc[c];
        ebP[7] = 0.f;
      }
    }
  } else {
    int idx = (b - 4) * 256 + threadIdx.x;       // 64 blocks -> 16384 = 2*16*512
    const int side = idx >= 16 * HD;
    if (side) idx -= 16 * HD;
    const float* WA = side ? WAm : WAu;
    const float* WB = side ? WBm : WBu;
    bf16* W2t = side ? W2m : W2u;
    int n = idx >> 9;
    int k = idx & (HD - 1);
    float v = 0.f;
    if (n < 7) v = WA[k * NC + n];
    else if (n >= 8 && n < 15) v = WB[k * NC + (n - 8)];
    W2t[(size_t)n * HD + k] = __float2bfloat16(v);
  }
}

// ---- merged layer-2 aggregation (concat dst space); 8 lanes per dst.
// Pab[NT][16]: cols 0..7 = row @ Wl_other (src contribution), 8..15 = row @ Wr_own.
__global__ __launch_bounds__(256) void agg_all_k(
    const float* __restrict__ Pab, const int* __restrict__ csrS,
    const int* __restrict__ off, const int* __restrict__ cnt,
    const float* __restrict__ eaSum,
    const float* __restrict__ ewP_u, const float* __restrict__ ebP_u,
    const float* __restrict__ cc_u, const float* __restrict__ ewP_m,
    const float* __restrict__ ebP_m, const float* __restrict__ cc_m,
    float* __restrict__ Pu, float* __restrict__ Pm)
{
  const int g = threadIdx.x >> 3;
  const int cl = threadIdx.x & 7;
  const int d = blockIdx.x * 32 + g;
  if (d >= NT) return;
  const int user = (d < NUU);
  const size_t srcbase = user ? (size_t)NUU : 0;
  const float* ewP = user ? ewP_u : ewP_m;
  const float* ebP = user ? ebP_u : ebP_m;
  const float* cc = user ? cc_u : cc_m;
  float* P = user ? Pu : Pm;
  const int dl = user ? d : d - NUU;
  const int deg = cnt[d];
  const int start = off[d];
  float a = 0.f;
  int i = 0;
  for (; i + 1 < deg; i += 2) {
    int s0 = csrS[start + i], s1 = csrS[start + i + 1];
    a += Pab[(srcbase + s0) * 16 + cl] + Pab[(srcbase + s1) * 16 + cl];
  }
  if (i < deg) a += Pab[(srcbase + csrS[start + i]) * 16 + cl];
  float r = Pab[(size_t)d * 16 + 8 + cl] + ((cl < 7) ? cc[cl] : 0.f);
  if (deg > 0) {
    float inv = 1.f / (float)deg;
    float es = 0.f;
#pragma unroll
    for (int j = 0; j < NC; ++j) es += eaSum[(size_t)d * 8 + j] * ewP[j * 8 + cl];
    r += (a + es) * inv + ebP[cl];
  }
  if (cl < 7) P[(size_t)dl * NC + cl] = r;
}

// ---- merged layer-1 SpMM over concat dst space; direct src ids (csrS) ----
__global__ __launch_bounds__(256) void spmm_all_k(
    const bf16* __restrict__ x_m, const bf16* __restrict__ ue_bf,
    const int* __restrict__ csrS, const int* __restrict__ off,
    const int* __restrict__ cnt, const float* __restrict__ eaSum,
    const float* __restrict__ ew_u, const float* __restrict__ eb_u,
    const float* __restrict__ ew_m, const float* __restrict__ eb_m,
    bf16* __restrict__ t)
{
  const int lane = threadIdx.x & 63;
  const int d = blockIdx.x * 4 + (threadIdx.x >> 6);
  if (d >= NT) return;
  const int user = (d < NUU);
  const bf16* __restrict__ xsrc = user ? x_m : ue_bf;
  const float* __restrict__ ew = user ? ew_u : ew_m;
  const float* __restrict__ eb = user ? eb_u : eb_m;
  const int deg = cnt[d];
  const int start = off[d];
  const int c0 = lane * 8;
  float acc[8] = {0.f, 0.f, 0.f, 0.f, 0.f, 0.f, 0.f, 0.f};
  int i = 0;
  for (; i + 3 < deg; i += 4) {
    int s0 = csrS[start + i], s1 = csrS[start + i + 1];
    int s2 = csrS[start + i + 2], s3 = csrS[start + i + 3];
    short8 v0 = *(const short8*)&xsrc[(size_t)s0 * HD + c0];
    short8 v1 = *(const short8*)&xsrc[(size_t)s1 * HD + c0];
    short8 v2 = *(const short8*)&xsrc[(size_t)s2 * HD + c0];
    short8 v3 = *(const short8*)&xsrc[(size_t)s3 * HD + c0];
#pragma unroll
    for (int j = 0; j < 8; ++j)
      acc[j] += (b2f((unsigned short)v0[j]) + b2f((unsigned short)v1[j])) +
                (b2f((unsigned short)v2[j]) + b2f((unsigned short)v3[j]));
  }
  for (; i < deg; ++i) {
    int s = csrS[start + i];
    short8 v = *(const short8*)&xsrc[(size_t)s * HD + c0];
#pragma unroll
    for (int j = 0; j < 8; ++j) acc[j] += b2f((unsigned short)v[j]);
  }
  short8 sv;
  if (deg > 0) {
    const float inv = 1.f / (float)deg;
    float es[8] = {0.f, 0.f, 0.f, 0.f, 0.f, 0.f, 0.f, 0.f};
#pragma unroll
    for (int j = 0; j < NC; ++j) {
      const float av = eaSum[(size_t)d * 8 + j];
      const float* __restrict__ wr = &ew[(size_t)j * HD + c0];
#pragma unroll
      for (int jj = 0; jj < 8; ++jj) es[jj] += av * wr[jj];
    }
#pragma unroll
    for (int jj = 0; jj < 8; ++jj)
      sv[jj] = (short)f2bbits((acc[jj] + es[jj]) * inv + eb[c0 + jj]);
  } else {
#pragma unroll
    for (int jj = 0; jj < 8; ++jj) sv[jj] = (short)f2bbits(0.f);
  }
  *(short8*)&t[(size_t)d * HD + c0] = sv;
}

// ---- merged MFMA GEMM (user wgs then movie wgs) + fused dual projection.
// Epilogue atomically accumulates the 4 n-tile partials into Pab[NT][16].
__global__ __launch_bounds__(256) void gemm_all_k(
    const bf16* __restrict__ tbuf, const bf16* __restrict__ ue_bf,
    const bf16* __restrict__ x_m, const bf16* __restrict__ Wcat_u,
    const bf16* __restrict__ Wcat_m, const float* __restrict__ bias_u,
    const float* __restrict__ bias_m, const bf16* __restrict__ W2t_u,
    const bf16* __restrict__ W2t_m, float* __restrict__ Pab, int nwgU)
{
  __shared__ __align__(16) char lds[34816];
  const int tid = threadIdx.x;
  const int lane = tid & 63;
  const int wid = tid >> 6;
  const int wr = wid >> 1, wc = wid & 1;
  const int lr = lane & 15, lk = lane >> 4;

  // XCD-bijective swizzle over combined grid (m204)
  const int nwg = gridDim.x;
  const int orig = blockIdx.x;
  const int q = nwg >> 3, r8 = nwg & 7;
  const int xcd = orig & 7, pos = orig >> 3;
  const int wg = (xcd < r8) ? xcd * (q + 1) + pos : r8 * (q + 1) + (xcd - r8) * q + pos;

  const int user = (wg < nwgU);
  const int wl = user ? wg : wg - nwgU;
  const bf16* __restrict__ A1 = user ? tbuf : tbuf + (size_t)NUU * HD;
  const bf16* __restrict__ A2 = user ? ue_bf : x_m;
  const bf16* __restrict__ Wcat = user ? Wcat_u : Wcat_m;
  const float* __restrict__ bias = user ? bias_u : bias_m;
  const bf16* __restrict__ W2t = user ? W2t_u : W2t_m;
  const int M = user ? NUU : NMM;
  const size_t rowbase = user ? 0 : (size_t)NUU;

  const int mt = wl >> 2, nt = wl & 3;
  const int m0 = mt * 128;
  const int n0 = nt * 128;

  const int srow = tid >> 2;
  const int sslot = tid & 3;

  f32x4 acc[4][4];
#pragma unroll
  for (int i = 0; i < 4; ++i)
#pragma unroll
    for (int j = 0; j < 4; ++j) acc[i][j] = (f32x4){0.f, 0.f, 0.f, 0.f};

  int gr0 = m0 + srow;       if (gr0 >= M) gr0 = M - 1;
  int gr1 = m0 + srow + 64;  if (gr1 >= M) gr1 = M - 1;
  const size_t aoff0 = (size_t)gr0 * HD + 8 * sslot;
  const size_t aoff1 = (size_t)gr1 * HD + 8 * sslot;
  const size_t boff0 = (size_t)(n0 + srow) * (2 * HD) + 8 * sslot;
  const size_t boff1 = (size_t)(n0 + srow + 64) * (2 * HD) + 8 * sslot;

  for (int ks = 0; ks < 32; ++ks) {
    const int k0 = ks * 32;
    const bf16* __restrict__ Ap = (k0 < HD) ? A1 : A2;
    const int ac = k0 & (HD - 1);
    gload16(Ap + aoff0 + ac, &lds[tid * 16]);
    gload16(Ap + aoff1 + ac, &lds[4096 + tid * 16]);
    gload16(Wcat + boff0 + k0, &lds[8192 + tid * 16]);
    gload16(Wcat + boff1 + k0, &lds[12288 + tid * 16]);
    __syncthreads();

    short8 af[4], bfr[4];
#pragma unroll
    for (int mf = 0; mf < 4; ++mf)
      af[mf] = *(const short8*)&lds[(wr * 64 + mf * 16 + lr) * 64 + lk * 16];
#pragma unroll
    for (int nf = 0; nf < 4; ++nf)
      bfr[nf] = *(const short8*)&lds[8192 + (wc * 64 + nf * 16 + lr) * 64 + lk * 16];
#pragma unroll
    for (int mf = 0; mf < 4; ++mf)
#pragma unroll
      for (int nf = 0; nf < 4; ++nf)
        acc[mf][nf] = __builtin_amdgcn_mfma_f32_16x16x32_bf16(
            af[mf], bfr[nf], acc[mf][nf], 0, 0, 0);
    __syncthreads();
  }

  // ---- epilogue: relu(z) -> LDS tile [128][136] bf16 ----
  bf16* zs = (bf16*)lds;
  const int ZLD = 136;
#pragma unroll
  for (int nf = 0; nf < 4; ++nf) {
    const int col_l = wc * 64 + nf * 16 + lr;
    const float bv = bias[n0 + col_l];
#pragma unroll
    for (int mf = 0; mf < 4; ++mf) {
      const int row_l = wr * 64 + mf * 16 + lk * 4;
#pragma unroll
      for (int r = 0; r < 4; ++r) {
        float v = fmaxf(acc[mf][nf][r] + bv, 0.f);
        zs[(size_t)(row_l + r) * ZLD + col_l] = __float2bfloat16(v);
      }
    }
  }
  __syncthreads();

  // ---- per-wave 32-row strip: Pab[row][0..15] += z_strip @ W2t^T ----
  const int strip = wid * 32;
  f32x4 p0 = {0.f, 0.f, 0.f, 0.f}, p1 = {0.f, 0.f, 0.f, 0.f};
#pragma unroll
  for (int kk = 0; kk < 4; ++kk) {
    short8 bfg = *(const short8*)&W2t[(size_t)lr * HD + n0 + kk * 32 + 8 * lk];
    short8 a0 = *(const short8*)&zs[(size_t)(strip + lr) * ZLD + kk * 32 + 8 * lk];
    short8 a1 = *(const short8*)&zs[(size_t)(strip + 16 + lr) * ZLD + kk * 32 + 8 * lk];
    p0 = __builtin_amdgcn_mfma_f32_16x16x32_bf16(a0, bfg, p0, 0, 0, 0);
    p1 = __builtin_amdgcn_mfma_f32_16x16x32_bf16(a1, bfg, p1, 0, 0, 0);
  }
#pragma unroll
  for (int r = 0; r < 4; ++r) {
    int row0 = m0 + strip + lk * 4 + r;
    if (row0 < M) atomicAdd(&Pab[(rowbase + row0) * 16 + lr], p0[r]);
    int row1 = m0 + strip + 16 + lk * 4 + r;
    if (row1 < M) atomicAdd(&Pab[(rowbase + row1) * 16 + lr], p1[r]);
  }
}

__global__ void gather_out_k(const float* __restrict__ Pu, const float* __restrict__ Pm,
                             const int* __restrict__ eli, const float* __restrict__ cb,
                             float* __restrict__ out)
{
  const int i = blockIdx.x * 256 + threadIdx.x;
  if (i >= NEL * NC) return;
  int e = i / NC;
  int c = i - e * NC;
  out[i] = Pu[(size_t)eli[e] * NC + c] + Pm[(size_t)eli[NEL + e] * NC + c] + cb[c];
}

// ---------------- host side ----------------
static inline char* bump(char*& p, size_t bytes)
{
  char* r = p;
  p += (bytes + 255) & ~(size_t)255;
  return r;
}

extern "C" void kernel_launch(void* const* d_in, const int* in_sizes, int n_in,
                              void* d_out, int out_size, void* d_ws, size_t ws_size,
                              hipStream_t stream)
{
  const float* movie_x   = (const float*)d_in[0];
  const float* user_emb  = (const float*)d_in[1];
  const float* movie_emb = (const float*)d_in[2];
  const float* mlw       = (const float*)d_in[3];
  const float* mlb       = (const float*)d_in[4];
  const float* ea_um     = (const float*)d_in[5];
  const float* ea_mu     = (const float*)d_in[6];
  const float* mu1_lw = (const float*)d_in[7];
  const float* mu1_lb = (const float*)d_in[8];
  const float* mu1_rw = (const float*)d_in[9];
  const float* mu1_ew = (const float*)d_in[10];
  const float* mu1_eb = (const float*)d_in[11];
  const float* um1_lw = (const float*)d_in[12];
  const float* um1_lb = (const float*)d_in[13];
  const float* um1_rw = (const float*)d_in[14];
  const float* um1_ew = (const float*)d_in[15];
  const float* um1_eb = (const float*)d_in[16];
  const float* mu2_lw = (const float*)d_in[17];
  const float* mu2_lb = (const float*)d_in[18];
  const float* mu2_rw = (const float*)d_in[19];
  const float* mu2_ew = (const float*)d_in[20];
  const float* mu2_eb = (const float*)d_in[21];
  const float* um2_lw = (const float*)d_in[22];
  const float* um2_lb = (const float*)d_in[23];
  const float* um2_rw = (const float*)d_in[24];
  const float* um2_ew = (const float*)d_in[25];
  const float* um2_eb = (const float*)d_in[26];
  const float* cls_w  = (const float*)d_in[27];
  const float* cls_b  = (const float*)d_in[28];
  const int*   ei_um  = (const int*)d_in[29];   // [2, E]: src(user), dst(movie)
  const int*   ei_mu  = (const int*)d_in[30];   // [2, E]: src(movie), dst(user)
  const int*   eli    = (const int*)d_in[31];   // [2, EL]
  float* out = (float*)d_out;

  char* w = (char*)d_ws;
  // --- zero-init region (one memset): cnt|fill, Pab, eaSum ---
  char* zbase = w;
  int* cf     = (int*)bump(w, (size_t)2 * NT * 4);   // cnt | fill
  int* cnt    = cf;
  int* fill   = cf + NT;
  float* Pab  = (float*)bump(w, (size_t)NT * 16 * 4);
  float* eaSum = (float*)bump(w, (size_t)NT * 8 * 4);
  size_t zbytes = (size_t)(w - zbase);
  // --- rest ---
  bf16* x_m   = (bf16*)bump(w, (size_t)NMM * HD * 2);
  bf16* tbuf  = (bf16*)bump(w, (size_t)NT * HD * 2);    // concat: user rows | movie rows
  bf16* ue_bf = (bf16*)bump(w, (size_t)NUU * HD * 2);
  bf16* Wcat_u1 = (bf16*)bump(w, (size_t)HD * 2 * HD * 2);
  bf16* Wcat_m1 = (bf16*)bump(w, (size_t)HD * 2 * HD * 2);
  float* Pu   = (float*)bump(w, (size_t)NUU * NC * 4);
  float* Pm   = (float*)bump(w, (size_t)NMM * NC * 4);
  float* Wl_u = (float*)bump(w, (size_t)HD * NC * 4);
  float* Wr_u = (float*)bump(w, (size_t)HD * NC * 4);
  float* cc_u = (float*)bump(w, 64 * 4);
  float* Wl_m = (float*)bump(w, (size_t)HD * NC * 4);
  float* Wr_m = (float*)bump(w, (size_t)HD * NC * 4);
  float* cc_m = (float*)bump(w, 64 * 4);
  bf16* W2t_u = (bf16*)bump(w, (size_t)16 * HD * 2);
  bf16* W2t_m = (bf16*)bump(w, (size_t)16 * HD * 2);
  float* ewP_u = (float*)bump(w, 64 * 4);
  float* ebP_u = (float*)bump(w, 64 * 4);
  float* ewP_m = (float*)bump(w, 64 * 4);
  float* ebP_m = (float*)bump(w, 64 * 4);
  int* off    = (int*)bump(w, (size_t)NT * 4);
  int* bsum   = (int*)bump(w, 256 * 4);
  int* csrS   = (int*)bump(w, (size_t)2 * NE * 4);

  const int GN = (NT + 511) / 512;    // 137 scan blocks

  hipMemsetAsync(zbase, 0, zbytes, stream);

  prep_k<<<2048, 256, 0, stream>>>(movie_x, mlw, mlb, movie_emb, x_m, user_emb, ue_bf);
  {
    dim3 g(HD / 32, 2 * HD / 32, 2);
    wtrans_k<<<g, 256, 0, stream>>>(mu1_lw, mu1_rw, Wcat_u1, um1_lw, um1_rw, Wcat_m1);
  }

  edge_pass_k<<<1024, 256, 0, stream>>>(ei_mu + NE, ei_um + NE, ea_mu, ea_um, cnt, eaSum);
  scan_a512<<<GN, 512, 0, stream>>>(cnt, off, bsum, NT);
  scan_b256<<<1, 256, 0, stream>>>(bsum, GN);
  scan_c512<<<GN, 512, 0, stream>>>(off, bsum, NT);
  fill2_k<<<1024, 256, 0, stream>>>(ei_mu, ei_mu + NE, ei_um, ei_um + NE,
                                    off, fill, csrS);

  {
    dim3 g(HD + 1, 2);
    projw_k<<<g, 64, 0, stream>>>(mu2_lw, mu2_rw, mu2_lb, cls_w, Wl_u, Wr_u, cc_u,
                                  um2_lw, um2_rw, um2_lb, Wl_m, Wr_m, cc_m);
  }
  p2w2t_k<<<68, 256, 0, stream>>>(mu2_ew, mu2_eb, Wl_u, ewP_u, ebP_u,
                                  um2_ew, um2_eb, Wl_m, ewP_m, ebP_m,
                                  Wl_m, Wr_u, W2t_u, Wl_u, Wr_m, W2t_m);

  // layer 1 (both sides)
  spmm_all_k<<<(NT + 3) / 4, 256, 0, stream>>>(x_m, ue_bf, csrS, off, cnt, eaSum,
                                               mu1_ew, mu1_eb, um1_ew, um1_eb, tbuf);
  const int nwgU = ((NUU + 127) / 128) * 4;   // 1564
  const int nwgM = ((NMM + 127) / 128) * 4;   // 628
  gemm_all_k<<<nwgU + nwgM, 256, 0, stream>>>(tbuf, ue_bf, x_m, Wcat_u1, Wcat_m1,
                                              mu1_lb, um1_lb, W2t_u, W2t_m,
                                              Pab, nwgU);

  agg_all_k<<<(NT + 31) / 32, 256, 0, stream>>>(Pab, csrS, off, cnt, eaSum,
                                                ewP_u, ebP_u, cc_u,
                                                ewP_m, ebP_m, cc_m, Pu, Pm);

  gather_out_k<<<(NEL * NC + 255) / 256, 256, 0, stream>>>(Pu, Pm, eli, cls_b, out);
}

// Round 9
// 363.441 us; speedup vs baseline: 1.4169x; 1.4169x over previous
//
#include <hip/hip_runtime.h>
#include <hip/hip_bf16.h>

#define NUU 50000
#define NMM 20000
#define NT (NUU + NMM)
#define FEAT 32
#define NE 262144
#define NEL 100000
#define HD 512
#define EDIM 7
#define NC 7

typedef __hip_bfloat16 bf16;
typedef __attribute__((ext_vector_type(8))) short short8;
typedef __attribute__((ext_vector_type(4))) float f32x4;

__device__ __forceinline__ float b2f(unsigned short u)
{
  return __uint_as_float((unsigned)u << 16);
}
__device__ __forceinline__ unsigned short f2bbits(float x)
{
  __hip_bfloat16 h = __float2bfloat16(x);
  return *reinterpret_cast<unsigned short*>(&h);
}
__device__ __forceinline__ float2 ld2(const float* p) { return *(const float2*)p; }
__device__ __forceinline__ void st2b(bf16* p, float x, float y)
{
  ushort2 u = make_ushort2(f2bbits(x), f2bbits(y));
  *(ushort2*)p = u;
}
__device__ __forceinline__ void gload16(const void* g, void* l)
{
  __builtin_amdgcn_global_load_lds(
      (const __attribute__((address_space(1))) void*)g,
      (__attribute__((address_space(3))) void*)l, 16, 0, 0);
}

// ---- merged prep: blocks [0,1024) encoder; [1024,2048) fp32->bf16 cvt of user_emb ----
__global__ __launch_bounds__(256) void prep_k(
    const float* __restrict__ mx, const float* __restrict__ W,
    const float* __restrict__ b, const float* __restrict__ emb,
    bf16* __restrict__ xm, const float* __restrict__ uin, bf16* __restrict__ ubf)
{
  const int tid = threadIdx.x;
  if (blockIdx.x < 1024) {
    const int c0 = 2 * tid;
    float2 wreg[FEAT];
#pragma unroll
    for (int k = 0; k < FEAT; ++k) wreg[k] = ld2(&W[(size_t)k * HD + c0]);
    const float2 bv = ld2(&b[c0]);
    __shared__ float xr[FEAT];
    for (int m = blockIdx.x; m < NMM; m += 1024) {
      if (tid < FEAT) xr[tid] = mx[(size_t)m * FEAT + tid];
      __syncthreads();
      float2 e2 = ld2(&emb[(size_t)m * HD + c0]);
      float s0 = bv.x + e2.x, s1 = bv.y + e2.y;
#pragma unroll
      for (int k = 0; k < FEAT; ++k) {
        s0 += xr[k] * wreg[k].x;
        s1 += xr[k] * wreg[k].y;
      }
      st2b(&xm[(size_t)m * HD + c0], s0, s1);
      __syncthreads();
    }
  } else {
    const int n4 = NUU * HD / 4;
    for (int i = (blockIdx.x - 1024) * 256 + tid; i < n4; i += 1024 * 256) {
      float4 v = *(const float4*)&uin[4 * (size_t)i];
      ushort4 u = make_ushort4(f2bbits(v.x), f2bbits(v.y), f2bbits(v.z), f2bbits(v.w));
      *(ushort4*)&ubf[4 * (size_t)i] = u;
    }
  }
}

// ---- merged Wcat transpose (z picks param set) ----
__global__ __launch_bounds__(256) void wtrans_k(
    const float* __restrict__ lwA, const float* __restrict__ rwA, bf16* __restrict__ WcA,
    const float* __restrict__ lwB, const float* __restrict__ rwB, bf16* __restrict__ WcB)
{
  const float* lw = blockIdx.z ? lwB : lwA;
  const float* rw = blockIdx.z ? rwB : rwA;
  bf16* Wcat = blockIdx.z ? WcB : WcA;
  __shared__ float s[32][33];
  const int tx = threadIdx.x & 31;
  const int ty = threadIdx.x >> 5;
  const int nt = blockIdx.x * 32;
  const int kt = blockIdx.y * 32;
#pragma unroll
  for (int q = 0; q < 4; ++q) {
    int k = kt + q * 8 + ty;
    int n = nt + tx;
    float v = (k < HD) ? lw[(size_t)k * HD + n] : rw[(size_t)(k - HD) * HD + n];
    s[q * 8 + ty][tx] = v;
  }
  __syncthreads();
#pragma unroll
  for (int q = 0; q < 4; ++q) {
    int n = nt + q * 8 + ty;
    int k = kt + tx;
    Wcat[(size_t)n * (2 * HD) + k] = __float2bfloat16(s[tx][q * 8 + ty]);
  }
}

// ---- degree count only (cheap int atomics) ----
__global__ void count2_k(const int* __restrict__ dmu, const int* __restrict__ dum,
                         int* __restrict__ cnt)
{
  for (int i = blockIdx.x * blockDim.x + threadIdx.x; i < NE; i += gridDim.x * blockDim.x) {
    atomicAdd(&cnt[dmu[i]], 1);
    atomicAdd(&cnt[NUU + dum[i]], 1);
  }
}

__global__ __launch_bounds__(512) void scan_a512(const int* __restrict__ in,
                                                 int* __restrict__ out,
                                                 int* __restrict__ bsum, int n)
{
  __shared__ int s[512];
  const int tid = threadIdx.x;
  const int i = blockIdx.x * 512 + tid;
  int v = (i < n) ? in[i] : 0;
  s[tid] = v;
  __syncthreads();
  for (int d = 1; d < 512; d <<= 1) {
    int t = (tid >= d) ? s[tid - d] : 0;
    __syncthreads();
    s[tid] += t;
    __syncthreads();
  }
  if (i < n) out[i] = s[tid] - v;           // exclusive
  if (tid == 511) bsum[blockIdx.x] = s[511];
}

__global__ void scan_b256(int* __restrict__ bsum, int nb)
{
  __shared__ int s[256];
  const int tid = threadIdx.x;
  int v = (tid < nb) ? bsum[tid] : 0;
  s[tid] = v;
  __syncthreads();
  for (int d = 1; d < 256; d <<= 1) {
    int t = (tid >= d) ? s[tid - d] : 0;
    __syncthreads();
    s[tid] += t;
    __syncthreads();
  }
  if (tid < nb) bsum[tid] = s[tid] - v;     // exclusive
}

__global__ __launch_bounds__(512) void scan_c512(int* __restrict__ out,
                                                 const int* __restrict__ bsum, int n)
{
  const int i = blockIdx.x * 512 + threadIdx.x;
  if (i < n) out[i] += bsum[blockIdx.x];
}

// fill CSR with edge id (for easum) and source node id (kills one indirection)
__global__ void fill2_k(const int* __restrict__ smu, const int* __restrict__ dmu,
                        const int* __restrict__ sum_, const int* __restrict__ dum,
                        const int* __restrict__ off, int* __restrict__ fill,
                        int* __restrict__ csrE, int* __restrict__ csrS)
{
  for (int i = blockIdx.x * blockDim.x + threadIdx.x; i < NE; i += gridDim.x * blockDim.x) {
    int d0 = dmu[i];
    int p0 = off[d0] + atomicAdd(&fill[d0], 1);
    csrE[p0] = i;
    csrS[p0] = smu[i];
    int d1 = NUU + dum[i];
    int p1 = off[d1] + atomicAdd(&fill[d1], 1);
    csrE[p1] = i;
    csrS[p1] = sum_[i];
  }
}

// ---- per-dst edge-attr sums (CSR-ordered reads, no atomics): eaSum[d][0..6], pad=0 ----
__global__ __launch_bounds__(256) void easum2_k(
    const float* __restrict__ eaMU, const float* __restrict__ eaUM,
    const int* __restrict__ csrE, const int* __restrict__ off,
    const int* __restrict__ cnt, float* __restrict__ eaSum)
{
  const int g = threadIdx.x >> 3;
  const int cl = threadIdx.x & 7;
  const int d = blockIdx.x * 32 + g;
  if (d >= NT) return;
  const float* __restrict__ ea = (d < NUU) ? eaMU : eaUM;
  const int deg = cnt[d];
  const int start = off[d];
  float a = 0.f;
  for (int i = 0; i < deg; ++i) {
    int e = csrE[start + i];
    if (cl < 7) a += ea[(size_t)e * EDIM + cl];
  }
  eaSum[(size_t)d * 8 + cl] = (cl < 7) ? a : 0.f;
}

// ---- folded classifier weights, both param sets in one launch (blockIdx.y) ----
__global__ __launch_bounds__(64) void projw_k(
    const float* __restrict__ lwA, const float* __restrict__ rwA,
    const float* __restrict__ lbA, const float* __restrict__ clsW,
    float* __restrict__ WlA, float* __restrict__ WrA, float* __restrict__ ccA,
    const float* __restrict__ lwB, const float* __restrict__ rwB,
    const float* __restrict__ lbB,
    float* __restrict__ WlB, float* __restrict__ WrB, float* __restrict__ ccB)
{
  const int side = blockIdx.y;
  const float* lw = side ? lwB : lwA;
  const float* rw = side ? rwB : rwA;
  const float* lb = side ? lbB : lbA;
  const float* cw = clsW + (side ? (size_t)HD * NC : 0);
  float* Wl = side ? WlB : WlA;
  float* Wr = side ? WrB : WrA;
  float* cc = side ? ccB : ccA;
  const int k = blockIdx.x;
  const int l = threadIdx.x;
  if (k < HD) {
    float aL[NC] = {0, 0, 0, 0, 0, 0, 0};
    float aR[NC] = {0, 0, 0, 0, 0, 0, 0};
    for (int j = l; j < HD; j += 64) {
      float a = lw[(size_t)k * HD + j];
      float b = rw[(size_t)k * HD + j];
#pragma unroll
      for (int c = 0; c < NC; ++c) {
        float w = cw[(size_t)j * NC + c];
        aL[c] += a * w;
        aR[c] += b * w;
      }
    }
#pragma unroll
    for (int c = 0; c < NC; ++c)
      for (int s = 32; s; s >>= 1) {
        aL[c] += __shfl_xor(aL[c], s);
        aR[c] += __shfl_xor(aR[c], s);
      }
    if (l == 0) {
#pragma unroll
      for (int c = 0; c < NC; ++c) {
        Wl[k * NC + c] = aL[c];
        Wr[k * NC + c] = aR[c];
      }
    }
  } else {
    float a0[NC] = {0, 0, 0, 0, 0, 0, 0};
    for (int j = l; j < HD; j += 64) {
      float a = lb[j];
#pragma unroll
      for (int c = 0; c < NC; ++c) a0[c] += a * cw[(size_t)j * NC + c];
    }
#pragma unroll
    for (int c = 0; c < NC; ++c)
      for (int s = 32; s; s >>= 1) a0[c] += __shfl_xor(a0[c], s);
    if (l == 0) {
#pragma unroll
      for (int c = 0; c < NC; ++c) cc[c] = a0[c];
    }
  }
}

// ---- merged: blocks 0..3 = proj2 fold; blocks 4..67 = W2t pack ----
__global__ __launch_bounds__(256) void p2w2t_k(
    const float* __restrict__ ewA, const float* __restrict__ ebA,
    const float* __restrict__ WlA, float* __restrict__ ewPA, float* __restrict__ ebPA,
    const float* __restrict__ ewB, const float* __restrict__ ebB,
    const float* __restrict__ WlB, float* __restrict__ ewPB, float* __restrict__ ebPB,
    const float* __restrict__ WAu, const float* __restrict__ WBu, bf16* __restrict__ W2u,
    const float* __restrict__ WAm, const float* __restrict__ WBm, bf16* __restrict__ W2m)
{
  const int b = blockIdx.x;
  if (b < 4) {
    const int side = b >> 1;
    const float* ew = side ? ewB : ewA;
    const float* ebv = side ? ebB : ebA;
    const float* Wl = side ? WlB : WlA;
    float* ewP = side ? ewPB : ewPA;
    float* ebP = side ? ebPB : ebPA;
    const int j = (b & 1) * 4 + (threadIdx.x >> 6);
    const int l = threadIdx.x & 63;
    const float* __restrict__ src = (j < 7) ? &ew[(size_t)j * HD] : ebv;
    float acc[NC] = {0, 0, 0, 0, 0, 0, 0};
    for (int k = l; k < HD; k += 64) {
      float v = src[k];
#pragma unroll
      for (int c = 0; c < NC; ++c) acc[c] += v * Wl[(size_t)k * NC + c];
    }
#pragma unroll
    for (int c = 0; c < NC; ++c)
      for (int s = 32; s; s >>= 1) acc[c] += __shfl_xor(acc[c], s);
    if (l == 0) {
      if (j < 7) {
#pragma unroll
        for (int c = 0; c < NC; ++c) ewP[j * 8 + c] = acc[c];
        ewP[j * 8 + 7] = 0.f;
      } else {
#pragma unroll
        for (int c = 0; c < NC; ++c) ebP[c] = acc[c];
        ebP[7] = 0.f;
      }
    }
  } else {
    int idx = (b - 4) * 256 + threadIdx.x;       // 64 blocks -> 16384 = 2*16*512
    const int side = idx >= 16 * HD;
    if (side) idx -= 16 * HD;
    const float* WA = side ? WAm : WAu;
    const float* WB = side ? WBm : WBu;
    bf16* W2t = side ? W2m : W2u;
    int n = idx >> 9;
    int k = idx & (HD - 1);
    float v = 0.f;
    if (n < 7) v = WA[k * NC + n];
    else if (n >= 8 && n < 15) v = WB[k * NC + (n - 8)];
    W2t[(size_t)n * HD + k] = __float2bfloat16(v);
  }
}

// ---- merged layer-2 aggregation (concat dst space); 8 lanes per dst.
// Pab[NT][16]: cols 0..7 = row @ Wl_other (src contribution), 8..15 = row @ Wr_own.
__global__ __launch_bounds__(256) void agg_all_k(
    const float* __restrict__ Pab, const int* __restrict__ csrS,
    const int* __restrict__ off, const int* __restrict__ cnt,
    const float* __restrict__ eaSum,
    const float* __restrict__ ewP_u, const float* __restrict__ ebP_u,
    const float* __restrict__ cc_u, const float* __restrict__ ewP_m,
    const float* __restrict__ ebP_m, const float* __restrict__ cc_m,
    float* __restrict__ Pu, float* __restrict__ Pm)
{
  const int g = threadIdx.x >> 3;
  const int cl = threadIdx.x & 7;
  const int d = blockIdx.x * 32 + g;
  if (d >= NT) return;
  const int user = (d < NUU);
  const size_t srcbase = user ? (size_t)NUU : 0;
  const float* ewP = user ? ewP_u : ewP_m;
  const float* ebP = user ? ebP_u : ebP_m;
  const float* cc = user ? cc_u : cc_m;
  float* P = user ? Pu : Pm;
  const int dl = user ? d : d - NUU;
  const int deg = cnt[d];
  const int start = off[d];
  float a = 0.f;
  int i = 0;
  for (; i + 1 < deg; i += 2) {
    int s0 = csrS[start + i], s1 = csrS[start + i + 1];
    a += Pab[(srcbase + s0) * 16 + cl] + Pab[(srcbase + s1) * 16 + cl];
  }
  if (i < deg) a += Pab[(srcbase + csrS[start + i]) * 16 + cl];
  float r = Pab[(size_t)d * 16 + 8 + cl] + ((cl < 7) ? cc[cl] : 0.f);
  if (deg > 0) {
    float inv = 1.f / (float)deg;
    float es = 0.f;
#pragma unroll
    for (int j = 0; j < NC; ++j) es += eaSum[(size_t)d * 8 + j] * ewP[j * 8 + cl];
    r += (a + es) * inv + ebP[cl];
  }
  if (cl < 7) P[(size_t)dl * NC + cl] = r;
}

// ---- merged layer-1 SpMM over concat dst space; direct src ids (csrS) ----
__global__ __launch_bounds__(256) void spmm_all_k(
    const bf16* __restrict__ x_m, const bf16* __restrict__ ue_bf,
    const int* __restrict__ csrS, const int* __restrict__ off,
    const int* __restrict__ cnt, const float* __restrict__ eaSum,
    const float* __restrict__ ew_u, const float* __restrict__ eb_u,
    const float* __restrict__ ew_m, const float* __restrict__ eb_m,
    bf16* __restrict__ t)
{
  const int lane = threadIdx.x & 63;
  const int d = blockIdx.x * 4 + (threadIdx.x >> 6);
  if (d >= NT) return;
  const int user = (d < NUU);
  const bf16* __restrict__ xsrc = user ? x_m : ue_bf;
  const float* __restrict__ ew = user ? ew_u : ew_m;
  const float* __restrict__ eb = user ? eb_u : eb_m;
  const int deg = cnt[d];
  const int start = off[d];
  const int c0 = lane * 8;
  float acc[8] = {0.f, 0.f, 0.f, 0.f, 0.f, 0.f, 0.f, 0.f};
  int i = 0;
  for (; i + 3 < deg; i += 4) {
    int s0 = csrS[start + i], s1 = csrS[start + i + 1];
    int s2 = csrS[start + i + 2], s3 = csrS[start + i + 3];
    short8 v0 = *(const short8*)&xsrc[(size_t)s0 * HD + c0];
    short8 v1 = *(const short8*)&xsrc[(size_t)s1 * HD + c0];
    short8 v2 = *(const short8*)&xsrc[(size_t)s2 * HD + c0];
    short8 v3 = *(const short8*)&xsrc[(size_t)s3 * HD + c0];
#pragma unroll
    for (int j = 0; j < 8; ++j)
      acc[j] += (b2f((unsigned short)v0[j]) + b2f((unsigned short)v1[j])) +
                (b2f((unsigned short)v2[j]) + b2f((unsigned short)v3[j]));
  }
  for (; i < deg; ++i) {
    int s = csrS[start + i];
    short8 v = *(const short8*)&xsrc[(size_t)s * HD + c0];
#pragma unroll
    for (int j = 0; j < 8; ++j) acc[j] += b2f((unsigned short)v[j]);
  }
  short8 sv;
  if (deg > 0) {
    const float inv = 1.f / (float)deg;
    float es[8] = {0.f, 0.f, 0.f, 0.f, 0.f, 0.f, 0.f, 0.f};
#pragma unroll
    for (int j = 0; j < NC; ++j) {
      const float av = eaSum[(size_t)d * 8 + j];
      const float* __restrict__ wr = &ew[(size_t)j * HD + c0];
#pragma unroll
      for (int jj = 0; jj < 8; ++jj) es[jj] += av * wr[jj];
    }
#pragma unroll
    for (int jj = 0; jj < 8; ++jj)
      sv[jj] = (short)f2bbits((acc[jj] + es[jj]) * inv + eb[c0 + jj]);
  } else {
#pragma unroll
    for (int jj = 0; jj < 8; ++jj) sv[jj] = (short)f2bbits(0.f);
  }
  *(short8*)&t[(size_t)d * HD + c0] = sv;
}

// ---- merged MFMA GEMM (user wgs then movie wgs) + fused dual projection.
// Epilogue atomically accumulates the 4 n-tile partials into Pab[NT][16].
__global__ __launch_bounds__(256) void gemm_all_k(
    const bf16* __restrict__ tbuf, const bf16* __restrict__ ue_bf,
    const bf16* __restrict__ x_m, const bf16* __restrict__ Wcat_u,
    const bf16* __restrict__ Wcat_m, const float* __restrict__ bias_u,
    const float* __restrict__ bias_m, const bf16* __restrict__ W2t_u,
    const bf16* __restrict__ W2t_m, float* __restrict__ Pab, int nwgU)
{
  __shared__ __align__(16) char lds[34816];
  const int tid = threadIdx.x;
  const int lane = tid & 63;
  const int wid = tid >> 6;
  const int wr = wid >> 1, wc = wid & 1;
  const int lr = lane & 15, lk = lane >> 4;

  // XCD-bijective swizzle over combined grid (m204)
  const int nwg = gridDim.x;
  const int orig = blockIdx.x;
  const int q = nwg >> 3, r8 = nwg & 7;
  const int xcd = orig & 7, pos = orig >> 3;
  const int wg = (xcd < r8) ? xcd * (q + 1) + pos : r8 * (q + 1) + (xcd - r8) * q + pos;

  const int user = (wg < nwgU);
  const int wl = user ? wg : wg - nwgU;
  const bf16* __restrict__ A1 = user ? tbuf : tbuf + (size_t)NUU * HD;
  const bf16* __restrict__ A2 = user ? ue_bf : x_m;
  const bf16* __restrict__ Wcat = user ? Wcat_u : Wcat_m;
  const float* __restrict__ bias = user ? bias_u : bias_m;
  const bf16* __restrict__ W2t = user ? W2t_u : W2t_m;
  const int M = user ? NUU : NMM;
  const size_t rowbase = user ? 0 : (size_t)NUU;

  const int mt = wl >> 2, nt = wl & 3;
  const int m0 = mt * 128;
  const int n0 = nt * 128;

  const int srow = tid >> 2;
  const int sslot = tid & 3;

  f32x4 acc[4][4];
#pragma unroll
  for (int i = 0; i < 4; ++i)
#pragma unroll
    for (int j = 0; j < 4; ++j) acc[i][j] = (f32x4){0.f, 0.f, 0.f, 0.f};

  int gr0 = m0 + srow;       if (gr0 >= M) gr0 = M - 1;
  int gr1 = m0 + srow + 64;  if (gr1 >= M) gr1 = M - 1;
  const size_t aoff0 = (size_t)gr0 * HD + 8 * sslot;
  const size_t aoff1 = (size_t)gr1 * HD + 8 * sslot;
  const size_t boff0 = (size_t)(n0 + srow) * (2 * HD) + 8 * sslot;
  const size_t boff1 = (size_t)(n0 + srow + 64) * (2 * HD) + 8 * sslot;

  for (int ks = 0; ks < 32; ++ks) {
    const int k0 = ks * 32;
    const bf16* __restrict__ Ap = (k0 < HD) ? A1 : A2;
    const int ac = k0 & (HD - 1);
    gload16(Ap + aoff0 + ac, &lds[tid * 16]);
    gload16(Ap + aoff1 + ac, &lds[4096 + tid * 16]);
    gload16(Wcat + boff0 + k0, &lds[8192 + tid * 16]);
    gload16(Wcat + boff1 + k0, &lds[12288 + tid * 16]);
    __syncthreads();

    short8 af[4], bfr[4];
#pragma unroll
    for (int mf = 0; mf < 4; ++mf)
      af[mf] = *(const short8*)&lds[(wr * 64 + mf * 16 + lr) * 64 + lk * 16];
#pragma unroll
    for (int nf = 0; nf < 4; ++nf)
      bfr[nf] = *(const short8*)&lds[8192 + (wc * 64 + nf * 16 + lr) * 64 + lk * 16];
#pragma unroll
    for (int mf = 0; mf < 4; ++mf)
#pragma unroll
      for (int nf = 0; nf < 4; ++nf)
        acc[mf][nf] = __builtin_amdgcn_mfma_f32_16x16x32_bf16(
            af[mf], bfr[nf], acc[mf][nf], 0, 0, 0);
    __syncthreads();
  }

  // ---- epilogue: relu(z) -> LDS tile [128][136] bf16 ----
  bf16* zs = (bf16*)lds;
  const int ZLD = 136;
#pragma unroll
  for (int nf = 0; nf < 4; ++nf) {
    const int col_l = wc * 64 + nf * 16 + lr;
    const float bv = bias[n0 + col_l];
#pragma unroll
    for (int mf = 0; mf < 4; ++mf) {
      const int row_l = wr * 64 + mf * 16 + lk * 4;
#pragma unroll
      for (int r = 0; r < 4; ++r) {
        float v = fmaxf(acc[mf][nf][r] + bv, 0.f);
        zs[(size_t)(row_l + r) * ZLD + col_l] = __float2bfloat16(v);
      }
    }
  }
  __syncthreads();

  // ---- per-wave 32-row strip: Pab[row][0..15] += z_strip @ W2t^T ----
  const int strip = wid * 32;
  f32x4 p0 = {0.f, 0.f, 0.f, 0.f}, p1 = {0.f, 0.f, 0.f, 0.f};
#pragma unroll
  for (int kk = 0; kk < 4; ++kk) {
    short8 bfg = *(const short8*)&W2t[(size_t)lr * HD + n0 + kk * 32 + 8 * lk];
    short8 a0 = *(const short8*)&zs[(size_t)(strip + lr) * ZLD + kk * 32 + 8 * lk];
    short8 a1 = *(const short8*)&zs[(size_t)(strip + 16 + lr) * ZLD + kk * 32 + 8 * lk];
    p0 = __builtin_amdgcn_mfma_f32_16x16x32_bf16(a0, bfg, p0, 0, 0, 0);
    p1 = __builtin_amdgcn_mfma_f32_16x16x32_bf16(a1, bfg, p1, 0, 0, 0);
  }
#pragma unroll
  for (int r = 0; r < 4; ++r) {
    int row0 = m0 + strip + lk * 4 + r;
    if (row0 < M) atomicAdd(&Pab[(rowbase + row0) * 16 + lr], p0[r]);
    int row1 = m0 + strip + 16 + lk * 4 + r;
    if (row1 < M) atomicAdd(&Pab[(rowbase + row1) * 16 + lr], p1[r]);
  }
}

__global__ void gather_out_k(const float* __restrict__ Pu, const float* __restrict__ Pm,
                             const int* __restrict__ eli, const float* __restrict__ cb,
                             float* __restrict__ out)
{
  const int i = blockIdx.x * 256 + threadIdx.x;
  if (i >= NEL * NC) return;
  int e = i / NC;
  int c = i - e * NC;
  out[i] = Pu[(size_t)eli[e] * NC + c] + Pm[(size_t)eli[NEL + e] * NC + c] + cb[c];
}

// ---------------- host side ----------------
static inline char* bump(char*& p, size_t bytes)
{
  char* r = p;
  p += (bytes + 255) & ~(size_t)255;
  return r;
}

extern "C" void kernel_launch(void* const* d_in, const int* in_sizes, int n_in,
                              void* d_out, int out_size, void* d_ws, size_t ws_size,
                              hipStream_t stream)
{
  const float* movie_x   = (const float*)d_in[0];
  const float* user_emb  = (const float*)d_in[1];
  const float* movie_emb = (const float*)d_in[2];
  const float* mlw       = (const float*)d_in[3];
  const float* mlb       = (const float*)d_in[4];
  const float* ea_um     = (const float*)d_in[5];
  const float* ea_mu     = (const float*)d_in[6];
  const float* mu1_lw = (const float*)d_in[7];
  const float* mu1_lb = (const float*)d_in[8];
  const float* mu1_rw = (const float*)d_in[9];
  const float* mu1_ew = (const float*)d_in[10];
  const float* mu1_eb = (const float*)d_in[11];
  const float* um1_lw = (const float*)d_in[12];
  const float* um1_lb = (const float*)d_in[13];
  const float* um1_rw = (const float*)d_in[14];
  const float* um1_ew = (const float*)d_in[15];
  const float* um1_eb = (const float*)d_in[16];
  const float* mu2_lw = (const float*)d_in[17];
  const float* mu2_lb = (const float*)d_in[18];
  const float* mu2_rw = (const float*)d_in[19];
  const float* mu2_ew = (const float*)d_in[20];
  const float* mu2_eb = (const float*)d_in[21];
  const float* um2_lw = (const float*)d_in[22];
  const float* um2_lb = (const float*)d_in[23];
  const float* um2_rw = (const float*)d_in[24];
  const float* um2_ew = (const float*)d_in[25];
  const float* um2_eb = (const float*)d_in[26];
  const float* cls_w  = (const float*)d_in[27];
  const float* cls_b  = (const float*)d_in[28];
  const int*   ei_um  = (const int*)d_in[29];   // [2, E]: src(user), dst(movie)
  const int*   ei_mu  = (const int*)d_in[30];   // [2, E]: src(movie), dst(user)
  const int*   eli    = (const int*)d_in[31];   // [2, EL]
  float* out = (float*)d_out;

  char* w = (char*)d_ws;
  // --- zero-init region (one memset): cnt|fill, Pab ---
  char* zbase = w;
  int* cf     = (int*)bump(w, (size_t)2 * NT * 4);   // cnt | fill
  int* cnt    = cf;
  int* fill   = cf + NT;
  float* Pab  = (float*)bump(w, (size_t)NT * 16 * 4);
  size_t zbytes = (size_t)(w - zbase);
  // --- rest ---
  float* eaSum = (float*)bump(w, (size_t)NT * 8 * 4);
  bf16* x_m   = (bf16*)bump(w, (size_t)NMM * HD * 2);
  bf16* tbuf  = (bf16*)bump(w, (size_t)NT * HD * 2);    // concat: user rows | movie rows
  bf16* ue_bf = (bf16*)bump(w, (size_t)NUU * HD * 2);
  bf16* Wcat_u1 = (bf16*)bump(w, (size_t)HD * 2 * HD * 2);
  bf16* Wcat_m1 = (bf16*)bump(w, (size_t)HD * 2 * HD * 2);
  float* Pu   = (float*)bump(w, (size_t)NUU * NC * 4);
  float* Pm   = (float*)bump(w, (size_t)NMM * NC * 4);
  float* Wl_u = (float*)bump(w, (size_t)HD * NC * 4);
  float* Wr_u = (float*)bump(w, (size_t)HD * NC * 4);
  float* cc_u = (float*)bump(w, 64 * 4);
  float* Wl_m = (float*)bump(w, (size_t)HD * NC * 4);
  float* Wr_m = (float*)bump(w, (size_t)HD * NC * 4);
  float* cc_m = (float*)bump(w, 64 * 4);
  bf16* W2t_u = (bf16*)bump(w, (size_t)16 * HD * 2);
  bf16* W2t_m = (bf16*)bump(w, (size_t)16 * HD * 2);
  float* ewP_u = (float*)bump(w, 64 * 4);
  float* ebP_u = (float*)bump(w, 64 * 4);
  float* ewP_m = (float*)bump(w, 64 * 4);
  float* ebP_m = (float*)bump(w, 64 * 4);
  int* off    = (int*)bump(w, (size_t)NT * 4);
  int* bsum   = (int*)bump(w, 256 * 4);
  int* csrE   = (int*)bump(w, (size_t)2 * NE * 4);
  int* csrS   = (int*)bump(w, (size_t)2 * NE * 4);

  const int GN = (NT + 511) / 512;    // 137 scan blocks

  hipMemsetAsync(zbase, 0, zbytes, stream);

  prep_k<<<2048, 256, 0, stream>>>(movie_x, mlw, mlb, movie_emb, x_m, user_emb, ue_bf);
  {
    dim3 g(HD / 32, 2 * HD / 32, 2);
    wtrans_k<<<g, 256, 0, stream>>>(mu1_lw, mu1_rw, Wcat_u1, um1_lw, um1_rw, Wcat_m1);
  }

  count2_k<<<1024, 256, 0, stream>>>(ei_mu + NE, ei_um + NE, cnt);
  scan_a512<<<GN, 512, 0, stream>>>(cnt, off, bsum, NT);
  scan_b256<<<1, 256, 0, stream>>>(bsum, GN);
  scan_c512<<<GN, 512, 0, stream>>>(off, bsum, NT);
  fill2_k<<<1024, 256, 0, stream>>>(ei_mu, ei_mu + NE, ei_um, ei_um + NE,
                                    off, fill, csrE, csrS);
  easum2_k<<<(NT + 31) / 32, 256, 0, stream>>>(ea_mu, ea_um, csrE, off, cnt, eaSum);

  {
    dim3 g(HD + 1, 2);
    projw_k<<<g, 64, 0, stream>>>(mu2_lw, mu2_rw, mu2_lb, cls_w, Wl_u, Wr_u, cc_u,
                                  um2_lw, um2_rw, um2_lb, Wl_m, Wr_m, cc_m);
  }
  p2w2t_k<<<68, 256, 0, stream>>>(mu2_ew, mu2_eb, Wl_u, ewP_u, ebP_u,
                                  um2_ew, um2_eb, Wl_m, ewP_m, ebP_m,
                                  Wl_m, Wr_u, W2t_u, Wl_u, Wr_m, W2t_m);

  // layer 1 (both sides)
  spmm_all_k<<<(NT + 3) / 4, 256, 0, stream>>>(x_m, ue_bf, csrS, off, cnt, eaSum,
                                               mu1_ew, mu1_eb, um1_ew, um1_eb, tbuf);
  const int nwgU = ((NUU + 127) / 128) * 4;   // 1564
  const int nwgM = ((NMM + 127) / 128) * 4;   // 628
  gemm_all_k<<<nwgU + nwgM, 256, 0, stream>>>(tbuf, ue_bf, x_m, Wcat_u1, Wcat_m1,
                                              mu1_lb, um1_lb, W2t_u, W2t_m,
                                              Pab, nwgU);

  agg_all_k<<<(NT + 31) / 32, 256, 0, stream>>>(Pab, csrS, off, cnt, eaSum,
                                                ewP_u, ebP_u, cc_u,
                                                ewP_m, ebP_m, cc_m, Pu, Pm);

  gather_out_k<<<(NEL * NC + 255) / 256, 256, 0, stream>>>(Pu, Pm, eli, cls_b, out);
}

// Round 10
// 330.637 us; speedup vs baseline: 1.5574x; 1.0992x over previous
//
#include <hip/hip_runtime.h>
#include <hip/hip_bf16.h>

#define NUU 50000
#define NMM 20000
#define NT (NUU + NMM)
#define FEAT 32
#define NE 262144
#define NEL 100000
#define HD 512
#define EDIM 7
#define NC 7

typedef __hip_bfloat16 bf16;
typedef __attribute__((ext_vector_type(8))) short short8;
typedef __attribute__((ext_vector_type(4))) float f32x4;

__device__ __forceinline__ float b2f(unsigned short u)
{
  return __uint_as_float((unsigned)u << 16);
}
__device__ __forceinline__ unsigned short f2bbits(float x)
{
  __hip_bfloat16 h = __float2bfloat16(x);
  return *reinterpret_cast<unsigned short*>(&h);
}
__device__ __forceinline__ float2 ld2(const float* p) { return *(const float2*)p; }
__device__ __forceinline__ void st2b(bf16* p, float x, float y)
{
  ushort2 u = make_ushort2(f2bbits(x), f2bbits(y));
  *(ushort2*)p = u;
}
__device__ __forceinline__ void gload16(const void* g, void* l)
{
  __builtin_amdgcn_global_load_lds(
      (const __attribute__((address_space(1))) void*)g,
      (__attribute__((address_space(3))) void*)l, 16, 0, 0);
}

// ---- phase1: [0,1024) encoder | [1024,2048) cvt | [2048,3072) wtrans | [3072,4096) count ----
__global__ __launch_bounds__(256) void phase1_k(
    const float* __restrict__ mx, const float* __restrict__ W,
    const float* __restrict__ b, const float* __restrict__ emb,
    bf16* __restrict__ xm, const float* __restrict__ uin, bf16* __restrict__ ubf,
    const float* __restrict__ lwA, const float* __restrict__ rwA, bf16* __restrict__ WcA,
    const float* __restrict__ lwB, const float* __restrict__ rwB, bf16* __restrict__ WcB,
    const int* __restrict__ dmu, const int* __restrict__ dum, int* __restrict__ cnt)
{
  const int tid = threadIdx.x;
  const int bx = blockIdx.x;
  if (bx < 1024) {
    // encoder: x_m = movie_x @ mlw + mlb + movie_emb (W slice in registers)
    const int c0 = 2 * tid;
    float2 wreg[FEAT];
#pragma unroll
    for (int k = 0; k < FEAT; ++k) wreg[k] = ld2(&W[(size_t)k * HD + c0]);
    const float2 bv = ld2(&b[c0]);
    __shared__ float xr[FEAT];
    for (int m = bx; m < NMM; m += 1024) {
      if (tid < FEAT) xr[tid] = mx[(size_t)m * FEAT + tid];
      __syncthreads();
      float2 e2 = ld2(&emb[(size_t)m * HD + c0]);
      float s0 = bv.x + e2.x, s1 = bv.y + e2.y;
#pragma unroll
      for (int k = 0; k < FEAT; ++k) {
        s0 += xr[k] * wreg[k].x;
        s1 += xr[k] * wreg[k].y;
      }
      st2b(&xm[(size_t)m * HD + c0], s0, s1);
      __syncthreads();
    }
  } else if (bx < 2048) {
    const int n4 = NUU * HD / 4;
    for (int i = (bx - 1024) * 256 + tid; i < n4; i += 1024 * 256) {
      float4 v = *(const float4*)&uin[4 * (size_t)i];
      ushort4 u = make_ushort4(f2bbits(v.x), f2bbits(v.y), f2bbits(v.z), f2bbits(v.w));
      *(ushort4*)&ubf[4 * (size_t)i] = u;
    }
  } else if (bx < 3072) {
    // Wcat transpose
    const int b2 = bx - 2048;
    const int side = b2 >> 9;
    const int rem = b2 & 511;
    const float* lw = side ? lwB : lwA;
    const float* rw = side ? rwB : rwA;
    bf16* Wcat = side ? WcB : WcA;
    __shared__ float s[32][33];
    const int tx = tid & 31;
    const int ty = tid >> 5;
    const int nt = (rem & 15) * 32;
    const int kt = (rem >> 4) * 32;
#pragma unroll
    for (int q = 0; q < 4; ++q) {
      int k = kt + q * 8 + ty;
      int n = nt + tx;
      float v = (k < HD) ? lw[(size_t)k * HD + n] : rw[(size_t)(k - HD) * HD + n];
      s[q * 8 + ty][tx] = v;
    }
    __syncthreads();
#pragma unroll
    for (int q = 0; q < 4; ++q) {
      int n = nt + q * 8 + ty;
      int k = kt + tx;
      Wcat[(size_t)n * (2 * HD) + k] = __float2bfloat16(s[tx][q * 8 + ty]);
    }
  } else {
    for (int i = (bx - 3072) * 256 + tid; i < NE; i += 1024 * 256) {
      atomicAdd(&cnt[dmu[i]], 1);
      atomicAdd(&cnt[NUU + dum[i]], 1);
    }
  }
}

// ---- blocks [0,GN): scan_a over cnt; blocks [GN, GN+129): projw units (8 warps/block) ----
__global__ __launch_bounds__(512) void scanA_projw_k(
    const int* __restrict__ in, int* __restrict__ out, int* __restrict__ bsum, int n,
    int GN,
    const float* __restrict__ lwA, const float* __restrict__ rwA,
    const float* __restrict__ lbA,
    const float* __restrict__ lwB, const float* __restrict__ rwB,
    const float* __restrict__ lbB, const float* __restrict__ clsW,
    float* __restrict__ WlA, float* __restrict__ WrA, float* __restrict__ ccA,
    float* __restrict__ WlB, float* __restrict__ WrB, float* __restrict__ ccB)
{
  const int tid = threadIdx.x;
  if ((int)blockIdx.x < GN) {
    __shared__ int s[512];
    const int i = blockIdx.x * 512 + tid;
    int v = (i < n) ? in[i] : 0;
    s[tid] = v;
    __syncthreads();
    for (int d = 1; d < 512; d <<= 1) {
      int t = (tid >= d) ? s[tid - d] : 0;
      __syncthreads();
      s[tid] += t;
      __syncthreads();
    }
    if (i < n) out[i] = s[tid] - v;           // exclusive
    if (tid == 511) bsum[blockIdx.x] = s[511];
    return;
  }
  const int unit = (blockIdx.x - GN) * 8 + (tid >> 6);
  if (unit >= 2 * (HD + 1)) return;
  const int side = unit / (HD + 1);
  const int k = unit % (HD + 1);
  const int l = tid & 63;
  const float* lw = side ? lwB : lwA;
  const float* rw = side ? rwB : rwA;
  const float* lb = side ? lbB : lbA;
  const float* cw = clsW + (side ? (size_t)HD * NC : 0);
  float* Wl = side ? WlB : WlA;
  float* Wr = side ? WrB : WrA;
  float* cc = side ? ccB : ccA;
  if (k < HD) {
    float aL[NC] = {0, 0, 0, 0, 0, 0, 0};
    float aR[NC] = {0, 0, 0, 0, 0, 0, 0};
    for (int j = l; j < HD; j += 64) {
      float a = lw[(size_t)k * HD + j];
      float b = rw[(size_t)k * HD + j];
#pragma unroll
      for (int c = 0; c < NC; ++c) {
        float w = cw[(size_t)j * NC + c];
        aL[c] += a * w;
        aR[c] += b * w;
      }
    }
#pragma unroll
    for (int c = 0; c < NC; ++c)
      for (int s2 = 32; s2; s2 >>= 1) {
        aL[c] += __shfl_xor(aL[c], s2);
        aR[c] += __shfl_xor(aR[c], s2);
      }
    if (l == 0) {
#pragma unroll
      for (int c = 0; c < NC; ++c) {
        Wl[k * NC + c] = aL[c];
        Wr[k * NC + c] = aR[c];
      }
    }
  } else {
    float a0[NC] = {0, 0, 0, 0, 0, 0, 0};
    for (int j = l; j < HD; j += 64) {
      float a = lb[j];
#pragma unroll
      for (int c = 0; c < NC; ++c) a0[c] += a * cw[(size_t)j * NC + c];
    }
#pragma unroll
    for (int c = 0; c < NC; ++c)
      for (int s2 = 32; s2; s2 >>= 1) a0[c] += __shfl_xor(a0[c], s2);
    if (l == 0) {
#pragma unroll
      for (int c = 0; c < NC; ++c) cc[c] = a0[c];
    }
  }
}

// ---- block 0: scan_b; blocks 1..68: p2w2t (proj2 fold + W2t pack) ----
__global__ __launch_bounds__(256) void scanB_p2w2t_k(
    int* __restrict__ bsum, int nb,
    const float* __restrict__ ewA, const float* __restrict__ ebA,
    const float* __restrict__ WlA, float* __restrict__ ewPA, float* __restrict__ ebPA,
    const float* __restrict__ ewB, const float* __restrict__ ebB,
    const float* __restrict__ WlB, float* __restrict__ ewPB, float* __restrict__ ebPB,
    const float* __restrict__ WAu, const float* __restrict__ WBu, bf16* __restrict__ W2u,
    const float* __restrict__ WAm, const float* __restrict__ WBm, bf16* __restrict__ W2m)
{
  const int tid = threadIdx.x;
  if (blockIdx.x == 0) {
    __shared__ int s[256];
    int v = (tid < nb) ? bsum[tid] : 0;
    s[tid] = v;
    __syncthreads();
    for (int d = 1; d < 256; d <<= 1) {
      int t = (tid >= d) ? s[tid - d] : 0;
      __syncthreads();
      s[tid] += t;
      __syncthreads();
    }
    if (tid < nb) bsum[tid] = s[tid] - v;     // exclusive
    return;
  }
  const int b = blockIdx.x - 1;
  if (b < 4) {
    const int side = b >> 1;
    const float* ew = side ? ewB : ewA;
    const float* ebv = side ? ebB : ebA;
    const float* Wl = side ? WlB : WlA;
    float* ewP = side ? ewPB : ewPA;
    float* ebP = side ? ebPB : ebPA;
    const int j = (b & 1) * 4 + (tid >> 6);
    const int l = tid & 63;
    const float* __restrict__ src = (j < 7) ? &ew[(size_t)j * HD] : ebv;
    float acc[NC] = {0, 0, 0, 0, 0, 0, 0};
    for (int k = l; k < HD; k += 64) {
      float v = src[k];
#pragma unroll
      for (int c = 0; c < NC; ++c) acc[c] += v * Wl[(size_t)k * NC + c];
    }
#pragma unroll
    for (int c = 0; c < NC; ++c)
      for (int s2 = 32; s2; s2 >>= 1) acc[c] += __shfl_xor(acc[c], s2);
    if (l == 0) {
      if (j < 7) {
#pragma unroll
        for (int c = 0; c < NC; ++c) ewP[j * 8 + c] = acc[c];
        ewP[j * 8 + 7] = 0.f;
      } else {
#pragma unroll
        for (int c = 0; c < NC; ++c) ebP[c] = acc[c];
        ebP[7] = 0.f;
      }
    }
  } else {
    int idx = (b - 4) * 256 + tid;       // 64 blocks -> 16384 = 2*16*512
    const int side = idx >= 16 * HD;
    if (side) idx -= 16 * HD;
    const float* WA = side ? WAm : WAu;
    const float* WB = side ? WBm : WBu;
    bf16* W2t = side ? W2m : W2u;
    int n = idx >> 9;
    int k = idx & (HD - 1);
    float v = 0.f;
    if (n < 7) v = WA[k * NC + n];
    else if (n >= 8 && n < 15) v = WB[k * NC + (n - 8)];
    W2t[(size_t)n * HD + k] = __float2bfloat16(v);
  }
}

__global__ __launch_bounds__(512) void scan_c512(int* __restrict__ out,
                                                 const int* __restrict__ bsum, int n)
{
  const int i = blockIdx.x * 512 + threadIdx.x;
  if (i < n) out[i] += bsum[blockIdx.x];
}

// fill CSR with {src id, edge id}
__global__ void fill2_k(const int* __restrict__ smu, const int* __restrict__ dmu,
                        const int* __restrict__ sum_, const int* __restrict__ dum,
                        const int* __restrict__ off, int* __restrict__ fill,
                        int2* __restrict__ csr2)
{
  for (int i = blockIdx.x * blockDim.x + threadIdx.x; i < NE; i += gridDim.x * blockDim.x) {
    int d0 = dmu[i];
    int p0 = off[d0] + atomicAdd(&fill[d0], 1);
    csr2[p0] = make_int2(smu[i], i);
    int d1 = NUU + dum[i];
    int p1 = off[d1] + atomicAdd(&fill[d1], 1);
    csr2[p1] = make_int2(sum_[i], i);
  }
}

// ---- merged layer-1 SpMM + fused per-dst ea-sum (lanes 0..6); writes eaSum for agg ----
__global__ __launch_bounds__(256) void spmm_all_k(
    const bf16* __restrict__ x_m, const bf16* __restrict__ ue_bf,
    const int2* __restrict__ csr2, const int* __restrict__ off,
    const int* __restrict__ cnt,
    const float* __restrict__ eaMU, const float* __restrict__ eaUM,
    const float* __restrict__ ew_u, const float* __restrict__ eb_u,
    const float* __restrict__ ew_m, const float* __restrict__ eb_m,
    float* __restrict__ eaSum, bf16* __restrict__ t)
{
  const int lane = threadIdx.x & 63;
  const int d = blockIdx.x * 4 + (threadIdx.x >> 6);
  if (d >= NT) return;
  const int user = (d < NUU);
  const bf16* __restrict__ xsrc = user ? x_m : ue_bf;
  const float* __restrict__ eaG = user ? eaMU : eaUM;
  const float* __restrict__ ew = user ? ew_u : ew_m;
  const float* __restrict__ eb = user ? eb_u : eb_m;
  const int deg = cnt[d];
  const int start = off[d];
  const int c0 = lane * 8;
  float acc[8] = {0.f, 0.f, 0.f, 0.f, 0.f, 0.f, 0.f, 0.f};
  float eacc = 0.f;
  int i = 0;
  for (; i + 3 < deg; i += 4) {
    int2 e0 = csr2[start + i], e1 = csr2[start + i + 1];
    int2 e2 = csr2[start + i + 2], e3 = csr2[start + i + 3];
    short8 v0 = *(const short8*)&xsrc[(size_t)e0.x * HD + c0];
    short8 v1 = *(const short8*)&xsrc[(size_t)e1.x * HD + c0];
    short8 v2 = *(const short8*)&xsrc[(size_t)e2.x * HD + c0];
    short8 v3 = *(const short8*)&xsrc[(size_t)e3.x * HD + c0];
    if (lane < 7)
      eacc += (eaG[(size_t)e0.y * EDIM + lane] + eaG[(size_t)e1.y * EDIM + lane]) +
              (eaG[(size_t)e2.y * EDIM + lane] + eaG[(size_t)e3.y * EDIM + lane]);
#pragma unroll
    for (int j = 0; j < 8; ++j)
      acc[j] += (b2f((unsigned short)v0[j]) + b2f((unsigned short)v1[j])) +
                (b2f((unsigned short)v2[j]) + b2f((unsigned short)v3[j]));
  }
  for (; i < deg; ++i) {
    int2 e = csr2[start + i];
    short8 v = *(const short8*)&xsrc[(size_t)e.x * HD + c0];
    if (lane < 7) eacc += eaG[(size_t)e.y * EDIM + lane];
#pragma unroll
    for (int j = 0; j < 8; ++j) acc[j] += b2f((unsigned short)v[j]);
  }
  if (lane < 8) eaSum[(size_t)d * 8 + lane] = (lane < 7) ? eacc : 0.f;
  short8 sv;
  if (deg > 0) {
    const float inv = 1.f / (float)deg;
    float es[8] = {0.f, 0.f, 0.f, 0.f, 0.f, 0.f, 0.f, 0.f};
#pragma unroll
    for (int j = 0; j < NC; ++j) {
      const float av = __shfl(eacc, j);
      const float* __restrict__ wr = &ew[(size_t)j * HD + c0];
#pragma unroll
      for (int jj = 0; jj < 8; ++jj) es[jj] += av * wr[jj];
    }
#pragma unroll
    for (int jj = 0; jj < 8; ++jj)
      sv[jj] = (short)f2bbits((acc[jj] + es[jj]) * inv + eb[c0 + jj]);
  } else {
#pragma unroll
    for (int jj = 0; jj < 8; ++jj) sv[jj] = (short)f2bbits(0.f);
  }
  *(short8*)&t[(size_t)d * HD + c0] = sv;
}

// ---- merged layer-2 aggregation (concat dst space); 8 lanes per dst.
// Pab[NT][16]: cols 0..7 = row @ Wl_other (src contribution), 8..15 = row @ Wr_own.
__global__ __launch_bounds__(256) void agg_all_k(
    const float* __restrict__ Pab, const int2* __restrict__ csr2,
    const int* __restrict__ off, const int* __restrict__ cnt,
    const float* __restrict__ eaSum,
    const float* __restrict__ ewP_u, const float* __restrict__ ebP_u,
    const float* __restrict__ cc_u, const float* __restrict__ ewP_m,
    const float* __restrict__ ebP_m, const float* __restrict__ cc_m,
    float* __restrict__ Pu, float* __restrict__ Pm)
{
  const int g = threadIdx.x >> 3;
  const int cl = threadIdx.x & 7;
  const int d = blockIdx.x * 32 + g;
  if (d >= NT) return;
  const int user = (d < NUU);
  const size_t srcbase = user ? (size_t)NUU : 0;
  const float* ewP = user ? ewP_u : ewP_m;
  const float* ebP = user ? ebP_u : ebP_m;
  const float* cc = user ? cc_u : cc_m;
  float* P = user ? Pu : Pm;
  const int dl = user ? d : d - NUU;
  const int deg = cnt[d];
  const int start = off[d];
  float a = 0.f;
  int i = 0;
  for (; i + 1 < deg; i += 2) {
    int s0 = csr2[start + i].x, s1 = csr2[start + i + 1].x;
    a += Pab[(srcbase + s0) * 16 + cl] + Pab[(srcbase + s1) * 16 + cl];
  }
  if (i < deg) a += Pab[(srcbase + csr2[start + i].x) * 16 + cl];
  float r = Pab[(size_t)d * 16 + 8 + cl] + ((cl < 7) ? cc[cl] : 0.f);
  if (deg > 0) {
    float inv = 1.f / (float)deg;
    float es = 0.f;
#pragma unroll
    for (int j = 0; j < NC; ++j) es += eaSum[(size_t)d * 8 + j] * ewP[j * 8 + cl];
    r += (a + es) * inv + ebP[cl];
  }
  if (cl < 7) P[(size_t)dl * NC + cl] = r;
}

// ---- merged MFMA GEMM (user wgs then movie wgs) + fused dual projection.
// Epilogue atomically accumulates the 4 n-tile partials into Pab[NT][16].
__global__ __launch_bounds__(256) void gemm_all_k(
    const bf16* __restrict__ tbuf, const bf16* __restrict__ ue_bf,
    const bf16* __restrict__ x_m, const bf16* __restrict__ Wcat_u,
    const bf16* __restrict__ Wcat_m, const float* __restrict__ bias_u,
    const float* __restrict__ bias_m, const bf16* __restrict__ W2t_u,
    const bf16* __restrict__ W2t_m, float* __restrict__ Pab, int nwgU)
{
  __shared__ __align__(16) char lds[34816];
  const int tid = threadIdx.x;
  const int lane = tid & 63;
  const int wid = tid >> 6;
  const int wr = wid >> 1, wc = wid & 1;
  const int lr = lane & 15, lk = lane >> 4;

  // XCD-bijective swizzle over combined grid (m204)
  const int nwg = gridDim.x;
  const int orig = blockIdx.x;
  const int q = nwg >> 3, r8 = nwg & 7;
  const int xcd = orig & 7, pos = orig >> 3;
  const int wg = (xcd < r8) ? xcd * (q + 1) + pos : r8 * (q + 1) + (xcd - r8) * q + pos;

  const int user = (wg < nwgU);
  const int wl = user ? wg : wg - nwgU;
  const bf16* __restrict__ A1 = user ? tbuf : tbuf + (size_t)NUU * HD;
  const bf16* __restrict__ A2 = user ? ue_bf : x_m;
  const bf16* __restrict__ Wcat = user ? Wcat_u : Wcat_m;
  const float* __restrict__ bias = user ? bias_u : bias_m;
  const bf16* __restrict__ W2t = user ? W2t_u : W2t_m;
  const int M = user ? NUU : NMM;
  const size_t rowbase = user ? 0 : (size_t)NUU;

  const int mt = wl >> 2, nt = wl & 3;
  const int m0 = mt * 128;
  const int n0 = nt * 128;

  const int srow = tid >> 2;
  const int sslot = tid & 3;

  f32x4 acc[4][4];
#pragma unroll
  for (int i = 0; i < 4; ++i)
#pragma unroll
    for (int j = 0; j < 4; ++j) acc[i][j] = (f32x4){0.f, 0.f, 0.f, 0.f};

  int gr0 = m0 + srow;       if (gr0 >= M) gr0 = M - 1;
  int gr1 = m0 + srow + 64;  if (gr1 >= M) gr1 = M - 1;
  const size_t aoff0 = (size_t)gr0 * HD + 8 * sslot;
  const size_t aoff1 = (size_t)gr1 * HD + 8 * sslot;
  const size_t boff0 = (size_t)(n0 + srow) * (2 * HD) + 8 * sslot;
  const size_t boff1 = (size_t)(n0 + srow + 64) * (2 * HD) + 8 * sslot;

  for (int ks = 0; ks < 32; ++ks) {
    const int k0 = ks * 32;
    const bf16* __restrict__ Ap = (k0 < HD) ? A1 : A2;
    const int ac = k0 & (HD - 1);
    gload16(Ap + aoff0 + ac, &lds[tid * 16]);
    gload16(Ap + aoff1 + ac, &lds[4096 + tid * 16]);
    gload16(Wcat + boff0 + k0, &lds[8192 + tid * 16]);
    gload16(Wcat + boff1 + k0, &lds[12288 + tid * 16]);
    __syncthreads();

    short8 af[4], bfr[4];
#pragma unroll
    for (int mf = 0; mf < 4; ++mf)
      af[mf] = *(const short8*)&lds[(wr * 64 + mf * 16 + lr) * 64 + lk * 16];
#pragma unroll
    for (int nf = 0; nf < 4; ++nf)
      bfr[nf] = *(const short8*)&lds[8192 + (wc * 64 + nf * 16 + lr) * 64 + lk * 16];
#pragma unroll
    for (int mf = 0; mf < 4; ++mf)
#pragma unroll
      for (int nf = 0; nf < 4; ++nf)
        acc[mf][nf] = __builtin_amdgcn_mfma_f32_16x16x32_bf16(
            af[mf], bfr[nf], acc[mf][nf], 0, 0, 0);
    __syncthreads();
  }

  // ---- epilogue: relu(z) -> LDS tile [128][136] bf16 ----
  bf16* zs = (bf16*)lds;
  const int ZLD = 136;
#pragma unroll
  for (int nf = 0; nf < 4; ++nf) {
    const int col_l = wc * 64 + nf * 16 + lr;
    const float bv = bias[n0 + col_l];
#pragma unroll
    for (int mf = 0; mf < 4; ++mf) {
      const int row_l = wr * 64 + mf * 16 + lk * 4;
#pragma unroll
      for (int r = 0; r < 4; ++r) {
        float v = fmaxf(acc[mf][nf][r] + bv, 0.f);
        zs[(size_t)(row_l + r) * ZLD + col_l] = __float2bfloat16(v);
      }
    }
  }
  __syncthreads();

  // ---- per-wave 32-row strip: Pab[row][0..15] += z_strip @ W2t^T ----
  const int strip = wid * 32;
  f32x4 p0 = {0.f, 0.f, 0.f, 0.f}, p1 = {0.f, 0.f, 0.f, 0.f};
#pragma unroll
  for (int kk = 0; kk < 4; ++kk) {
    short8 bfg = *(const short8*)&W2t[(size_t)lr * HD + n0 + kk * 32 + 8 * lk];
    short8 a0 = *(const short8*)&zs[(size_t)(strip + lr) * ZLD + kk * 32 + 8 * lk];
    short8 a1 = *(const short8*)&zs[(size_t)(strip + 16 + lr) * ZLD + kk * 32 + 8 * lk];
    p0 = __builtin_amdgcn_mfma_f32_16x16x32_bf16(a0, bfg, p0, 0, 0, 0);
    p1 = __builtin_amdgcn_mfma_f32_16x16x32_bf16(a1, bfg, p1, 0, 0, 0);
  }
#pragma unroll
  for (int r = 0; r < 4; ++r) {
    int row0 = m0 + strip + lk * 4 + r;
    if (row0 < M) atomicAdd(&Pab[(rowbase + row0) * 16 + lr], p0[r]);
    int row1 = m0 + strip + 16 + lk * 4 + r;
    if (row1 < M) atomicAdd(&Pab[(rowbase + row1) * 16 + lr], p1[r]);
  }
}

__global__ void gather_out_k(const float* __restrict__ Pu, const float* __restrict__ Pm,
                             const int* __restrict__ eli, const float* __restrict__ cb,
                             float* __restrict__ out)
{
  const int i = blockIdx.x * 256 + threadIdx.x;
  if (i >= NEL * NC) return;
  int e = i / NC;
  int c = i - e * NC;
  out[i] = Pu[(size_t)eli[e] * NC + c] + Pm[(size_t)eli[NEL + e] * NC + c] + cb[c];
}

// ---------------- host side ----------------
static inline char* bump(char*& p, size_t bytes)
{
  char* r = p;
  p += (bytes + 255) & ~(size_t)255;
  return r;
}

extern "C" void kernel_launch(void* const* d_in, const int* in_sizes, int n_in,
                              void* d_out, int out_size, void* d_ws, size_t ws_size,
                              hipStream_t stream)
{
  const float* movie_x   = (const float*)d_in[0];
  const float* user_emb  = (const float*)d_in[1];
  const float* movie_emb = (const float*)d_in[2];
  const float* mlw       = (const float*)d_in[3];
  const float* mlb       = (const float*)d_in[4];
  const float* ea_um     = (const float*)d_in[5];
  const float* ea_mu     = (const float*)d_in[6];
  const float* mu1_lw = (const float*)d_in[7];
  const float* mu1_lb = (const float*)d_in[8];
  const float* mu1_rw = (const float*)d_in[9];
  const float* mu1_ew = (const float*)d_in[10];
  const float* mu1_eb = (const float*)d_in[11];
  const float* um1_lw = (const float*)d_in[12];
  const float* um1_lb = (const float*)d_in[13];
  const float* um1_rw = (const float*)d_in[14];
  const float* um1_ew = (const float*)d_in[15];
  const float* um1_eb = (const float*)d_in[16];
  const float* mu2_lw = (const float*)d_in[17];
  const float* mu2_lb = (const float*)d_in[18];
  const float* mu2_rw = (const float*)d_in[19];
  const float* mu2_ew = (const float*)d_in[20];
  const float* mu2_eb = (const float*)d_in[21];
  const float* um2_lw = (const float*)d_in[22];
  const float* um2_lb = (const float*)d_in[23];
  const float* um2_rw = (const float*)d_in[24];
  const float* um2_ew = (const float*)d_in[25];
  const float* um2_eb = (const float*)d_in[26];
  const float* cls_w  = (const float*)d_in[27];
  const float* cls_b  = (const float*)d_in[28];
  const int*   ei_um  = (const int*)d_in[29];   // [2, E]: src(user), dst(movie)
  const int*   ei_mu  = (const int*)d_in[30];   // [2, E]: src(movie), dst(user)
  const int*   eli    = (const int*)d_in[31];   // [2, EL]
  float* out = (float*)d_out;

  char* w = (char*)d_ws;
  // --- zero-init region (one memset): cnt|fill, Pab ---
  char* zbase = w;
  int* cf     = (int*)bump(w, (size_t)2 * NT * 4);   // cnt | fill
  int* cnt    = cf;
  int* fill   = cf + NT;
  float* Pab  = (float*)bump(w, (size_t)NT * 16 * 4);
  size_t zbytes = (size_t)(w - zbase);
  // --- rest ---
  float* eaSum = (float*)bump(w, (size_t)NT * 8 * 4);
  bf16* x_m   = (bf16*)bump(w, (size_t)NMM * HD * 2);
  bf16* tbuf  = (bf16*)bump(w, (size_t)NT * HD * 2);    // concat: user rows | movie rows
  bf16* ue_bf = (bf16*)bump(w, (size_t)NUU * HD * 2);
  bf16* Wcat_u1 = (bf16*)bump(w, (size_t)HD * 2 * HD * 2);
  bf16* Wcat_m1 = (bf16*)bump(w, (size_t)HD * 2 * HD * 2);
  float* Pu   = (float*)bump(w, (size_t)NUU * NC * 4);
  float* Pm   = (float*)bump(w, (size_t)NMM * NC * 4);
  float* Wl_u = (float*)bump(w, (size_t)HD * NC * 4);
  float* Wr_u = (float*)bump(w, (size_t)HD * NC * 4);
  float* cc_u = (float*)bump(w, 64 * 4);
  float* Wl_m = (float*)bump(w, (size_t)HD * NC * 4);
  float* Wr_m = (float*)bump(w, (size_t)HD * NC * 4);
  float* cc_m = (float*)bump(w, 64 * 4);
  bf16* W2t_u = (bf16*)bump(w, (size_t)16 * HD * 2);
  bf16* W2t_m = (bf16*)bump(w, (size_t)16 * HD * 2);
  float* ewP_u = (float*)bump(w, 64 * 4);
  float* ebP_u = (float*)bump(w, 64 * 4);
  float* ewP_m = (float*)bump(w, 64 * 4);
  float* ebP_m = (float*)bump(w, 64 * 4);
  int* off    = (int*)bump(w, (size_t)NT * 4);
  int* bsum   = (int*)bump(w, 256 * 4);
  int2* csr2  = (int2*)bump(w, (size_t)2 * NE * 8);

  const int GN = (NT + 511) / 512;    // 137 scan blocks
  const int PJB = (2 * (HD + 1) + 7) / 8;   // 129 projw blocks

  hipMemsetAsync(zbase, 0, zbytes, stream);

  phase1_k<<<4096, 256, 0, stream>>>(movie_x, mlw, mlb, movie_emb, x_m,
                                     user_emb, ue_bf,
                                     mu1_lw, mu1_rw, Wcat_u1,
                                     um1_lw, um1_rw, Wcat_m1,
                                     ei_mu + NE, ei_um + NE, cnt);

  scanA_projw_k<<<GN + PJB, 512, 0, stream>>>(cnt, off, bsum, NT, GN,
                                              mu2_lw, mu2_rw, mu2_lb,
                                              um2_lw, um2_rw, um2_lb, cls_w,
                                              Wl_u, Wr_u, cc_u, Wl_m, Wr_m, cc_m);

  scanB_p2w2t_k<<<69, 256, 0, stream>>>(bsum, GN,
                                        mu2_ew, mu2_eb, Wl_u, ewP_u, ebP_u,
                                        um2_ew, um2_eb, Wl_m, ewP_m, ebP_m,
                                        Wl_m, Wr_u, W2t_u, Wl_u, Wr_m, W2t_m);

  scan_c512<<<GN, 512, 0, stream>>>(off, bsum, NT);
  fill2_k<<<1024, 256, 0, stream>>>(ei_mu, ei_mu + NE, ei_um, ei_um + NE,
                                    off, fill, csr2);

  spmm_all_k<<<(NT + 3) / 4, 256, 0, stream>>>(x_m, ue_bf, csr2, off, cnt,
                                               ea_mu, ea_um,
                                               mu1_ew, mu1_eb, um1_ew, um1_eb,
                                               eaSum, tbuf);

  const int nwgU = ((NUU + 127) / 128) * 4;   // 1564
  const int nwgM = ((NMM + 127) / 128) * 4;   // 628
  gemm_all_k<<<nwgU + nwgM, 256, 0, stream>>>(tbuf, ue_bf, x_m, Wcat_u1, Wcat_m1,
                                              mu1_lb, um1_lb, W2t_u, W2t_m,
                                              Pab, nwgU);

  agg_all_k<<<(NT + 31) / 32, 256, 0, stream>>>(Pab, csr2, off, cnt, eaSum,
                                                ewP_u, ebP_u, cc_u,
                                                ewP_m, ebP_m, cc_m, Pu, Pm);

  gather_out_k<<<(NEL * NC + 255) / 256, 256, 0, stream>>>(Pu, Pm, eli, cls_b, out);
}